// Round 3
// baseline (85.329 us; speedup 1.0000x reference)
//
#include <hip/hip_runtime.h>
#include <math.h>

#define N_GAUSS 1536
#define WIDTH   160
#define HEIGHT  128
#define FXC     146.44f
#define FYC     146.44f
#define CXC     80.0f
#define CYC     64.0f
#define EPS2D   0.3f
#define NEARP   0.01f
#define FARP    1e10f
#define L2E     1.4426950408889634f
#define LN2     0.6931471805599453f
#define CULL_E  25.0f              // cull where alpha <= 2^-25 (err <= 1536*2^-25 ~ 4.6e-5)

#define TPB     1024
#define NWAVE   16                 // waves per block = depth chunks in composite
#define TILE_W  8
#define TILE_H  8
#define TILES_X (WIDTH / TILE_W)   // 20
#define TILES_Y (HEIGHT / TILE_H)  // 16
#define NTILES  (TILES_X * TILES_Y) // 320
#define RBLOCKS 256                // 1 block/CU (114KB LDS); blocks 0..63 take 2 light tiles

// LDS layout (bytes). All offsets 16B-aligned.
//  srec [1536*3 float4] : (u,v,a2,b2) (c2,o2,r,g) (b,-,-,-) per survivor slot
//  key64[1536 u64]      : (asuint(depth)<<32)|gid  -- sort key, total order
//  rnk  [1536 i32]      : rank accumulation (atomicAdd partials)
//  ord  [1536 i32]      : rank -> slot permutation
//  part [16*64 float4]  : per-wave compositing partials
#define OFF_REC   0
#define OFF_KEY   73728
#define OFF_RNK   86016
#define OFF_ORD   92160
#define OFF_PART  98304
#define OFF_CNT   114688
#define SMEM_SZ   114704

// fast 2^x: single v_exp_f32 on gfx950
__device__ __forceinline__ float fast_exp2(float x) {
    return __builtin_amdgcn_exp2f(x);
}

// Single fused kernel: projection + per-tile cull + per-tile exact depth sort
// + composite. Correctness of per-tile sort: a pixel's composite depends only
// on the relative depth order of the gaussians contributing to it; sorting
// this tile's survivors by (depth, index) equals the reference's global
// stable argsort restricted to that subset. Masked gaussians never survive
// (hit=false), matching alpha=0 in the reference. No cross-block FP
// consistency needed anymore: each pixel is produced wholly by one block.
__global__ __launch_bounds__(TPB) void fused_kernel(
    const float* __restrict__ means, const float* __restrict__ quats,
    const float* __restrict__ log_scales, const float* __restrict__ opac_logits,
    const float* __restrict__ sh, const float* __restrict__ c2w,
    float* __restrict__ out)
{
    extern __shared__ unsigned char smem[];
    float4*             srec  = (float4*)(smem + OFF_REC);
    unsigned long long* key64 = (unsigned long long*)(smem + OFF_KEY);
    int*                rnk   = (int*)(smem + OFF_RNK);
    int*                ord   = (int*)(smem + OFF_ORD);
    float4*             part  = (float4*)(smem + OFF_PART);
    int*                cntp  = (int*)(smem + OFF_CNT);

    int tid  = threadIdx.x;
    int wave = __builtin_amdgcn_readfirstlane(tid >> 6);
    int lane = tid & 63;

    // camera: c2w is (3,4) row-major. R = c2w[:,:3] with columns 1,2 negated.
    float C[12];
#pragma unroll
    for (int k = 0; k < 12; k++) C[k] = c2w[k];
    float R00 =  C[0], R01 =  C[4], R02 =  C[8];
    float R10 = -C[1], R11 = -C[5], R12 = -C[9];
    float R20 = -C[2], R21 = -C[6], R22 = -C[10];
    float cpx = C[3], cpy = C[7], cpz = C[11];
    float t0 = -(R00 * cpx + R01 * cpy + R02 * cpz);
    float t1 = -(R10 * cpx + R11 * cpy + R12 * cpz);
    float t2 = -(R20 * cpx + R21 * cpy + R22 * cpz);

    // blocks 0..63 pair their (light, top-row) tile with a (light, bottom-row)
    // tile 256+b; heavy central tiles get a whole CU to themselves.
    int ntile = (blockIdx.x < NTILES - RBLOCKS) ? 2 : 1;
    for (int ti = 0; ti < ntile; ti++) {
        int tile = (ti == 0) ? (int)blockIdx.x : (RBLOCKS + (int)blockIdx.x);
        int tx0 = (tile % TILES_X) * TILE_W;
        int ty0 = (tile / TILES_X) * TILE_H;
        float px = (float)(tx0 + (lane & 7));
        float py = (float)(ty0 + (lane >> 3));
        float tcx = (float)tx0 + 3.5f;         // tile center; max pixel offset 3.5
        float tcy = (float)ty0 + 3.5f;

        if (tid == 0) *cntp = 0;
        rnk[tid] = 0;
        if (tid < N_GAUSS - TPB) rnk[TPB + tid] = 0;
        __syncthreads();

        // ---- Phase A: project ALL 1536, cull vs this tile, compact survivors.
        int slotA = -1, slotB = -1;
#pragma unroll
        for (int rep = 0; rep < 2; rep++) {
            int g = tid + (rep << 10);
            if (g < N_GAUSS) {           // rep=1: waves 0..7 only (wave-uniform)
                float mx = means[3 * g], my = means[3 * g + 1], mz = means[3 * g + 2];
                float4 qv = ((const float4*)quats)[g];
                float lsx = log_scales[3 * g + 0];
                float lsy = log_scales[3 * g + 1];
                float lsz = log_scales[3 * g + 2];
                float olog = opac_logits[g];

                float tx = R00 * mx + R01 * my + R02 * mz + t0;
                float ty = R10 * mx + R11 * my + R12 * mz + t1;
                float tz = R20 * mx + R21 * my + R22 * mz + t2;
                bool mask = (tz > NEARP) && (tz < FARP);

                // quat -> rot, scaled columns, cov3d = M M^T
                float qw = qv.x, qx = qv.y, qy = qv.z, qz = qv.w;
                float qn = rsqrtf(qw * qw + qx * qx + qy * qy + qz * qz);
                qw *= qn; qx *= qn; qy *= qn; qz *= qn;
                float sx = expf(lsx);
                float sy = expf(lsy);
                float sz = expf(lsz);
                float M00 = (1.f - 2.f * (qy * qy + qz * qz)) * sx;
                float M01 = (2.f * (qx * qy - qz * qw)) * sy;
                float M02 = (2.f * (qx * qz + qy * qw)) * sz;
                float M10 = (2.f * (qx * qy + qz * qw)) * sx;
                float M11 = (1.f - 2.f * (qx * qx + qz * qz)) * sy;
                float M12 = (2.f * (qy * qz - qx * qw)) * sz;
                float M20 = (2.f * (qx * qz - qy * qw)) * sx;
                float M21 = (2.f * (qy * qz + qx * qw)) * sy;
                float M22 = (1.f - 2.f * (qx * qx + qy * qy)) * sz;
                float V00 = M00 * M00 + M01 * M01 + M02 * M02;
                float V01 = M00 * M10 + M01 * M11 + M02 * M12;
                float V02 = M00 * M20 + M01 * M21 + M02 * M22;
                float V11 = M10 * M10 + M11 * M11 + M12 * M12;
                float V12 = M10 * M20 + M11 * M21 + M12 * M22;
                float V22 = M20 * M20 + M21 * M21 + M22 * M22;

                // cov_cam = Rw V Rw^T
                float T00 = R00 * V00 + R01 * V01 + R02 * V02;
                float T01 = R00 * V01 + R01 * V11 + R02 * V12;
                float T02 = R00 * V02 + R01 * V12 + R02 * V22;
                float T10 = R10 * V00 + R11 * V01 + R12 * V02;
                float T11 = R10 * V01 + R11 * V11 + R12 * V12;
                float T12 = R10 * V02 + R11 * V12 + R12 * V22;
                float T20 = R20 * V00 + R21 * V01 + R22 * V02;
                float T21 = R20 * V01 + R21 * V11 + R22 * V12;
                float T22 = R20 * V02 + R21 * V12 + R22 * V22;
                float cc00 = T00 * R00 + T01 * R01 + T02 * R02;
                float cc01 = T00 * R10 + T01 * R11 + T02 * R12;
                float cc02 = T00 * R20 + T01 * R21 + T02 * R22;
                float cc11 = T10 * R10 + T11 * R11 + T12 * R12;
                float cc12 = T10 * R20 + T11 * R21 + T12 * R22;
                float cc22 = T20 * R20 + T21 * R21 + T22 * R22;

                // projection Jacobian, cov2d = J cov_cam J^T
                float rz = 1.f / tz;
                float rz2 = rz * rz;
                float j00 = FXC * rz, j02 = -FXC * tx * rz2;
                float j11 = FYC * rz, j12 = -FYC * ty * rz2;
                float c2d00 = j00 * j00 * cc00 + 2.f * j00 * j02 * cc02 + j02 * j02 * cc22;
                float c2d01 = (j00 * cc01 + j02 * cc12) * j11 + (j00 * cc02 + j02 * cc22) * j12;
                float c2d11 = j11 * j11 * cc11 + 2.f * j11 * j12 * cc12 + j12 * j12 * cc22;

                float a = c2d00 + EPS2D, c = c2d11 + EPS2D, b = c2d01;
                float idet = 1.f / (a * c - b * b);
                float Ac = c * idet, Bc = -b * idet, Cc = a * idet;
                float u = FXC * tx * rz + CXC;
                float v = FYC * ty * rz + CYC;
                float op = 1.f / (1.f + expf(-olog));
                float a2 = -0.5f * L2E * Ac;
                float b2 = -L2E * Bc;
                float c2 = -0.5f * L2E * Cc;
                float o2 = log2f(op);

                // exact ellipse AABB at alpha = 2^-CULL_E
                float Qmax = fmaxf(0.f, 2.f * LN2 * (CULL_E + o2));
                float rx = sqrtf(Qmax * a);
                float ry = sqrtf(Qmax * c);
                bool hit = mask && (fabsf(tcx - u) <= rx + 3.5f)
                                && (fabsf(tcy - v) <= ry + 3.5f);

                // wave-aggregated compaction (1 LDS atomic per wave)
                unsigned long long hm = __ballot(hit);
                int base = 0;
                if (lane == 0) {
                    int nw = __popcll(hm);
                    if (nw) base = atomicAdd(cntp, nw);
                }
                base = __shfl(base, 0);
                if (hit) {
                    int slot = base + __popcll(hm & ((1ull << lane) - 1ull));
                    srec[3 * slot + 0] = make_float4(u, v, a2, b2);
                    srec[3 * slot + 1] = make_float4(c2, o2, 0.f, 0.f);
                    key64[slot] = (((unsigned long long)__float_as_uint(tz)) << 32)
                                  | (unsigned long long)(unsigned)g;
                    if (rep == 0) slotA = slot; else slotB = slot;
                }
            }
        }
        __syncthreads();
        int cnt = __builtin_amdgcn_readfirstlane(*cntp);

        // ---- Phase B: SH colors for survivors only (dense over cnt), then
        // distributed rank count. No sync between the two: SH writes srec
        // color fields, rank reads key64 -- disjoint, and SH load latency
        // overlaps rank compute.
        for (int s = tid; s < cnt; s += TPB) {
            int g = (int)(key64[s] & 0xffffffffull);
            float mx = means[3 * g], my = means[3 * g + 1], mz = means[3 * g + 2];
            float dxv = mx - cpx, dyv = my - cpy, dzv = mz - cpz;
            float rn = rsqrtf(dxv * dxv + dyv * dyv + dzv * dzv);
            float x = dxv * rn, y = dyv * rn, z = dzv * rn;
            float xx = x * x, yy = y * y, zz = z * z;
            float basis[16];
            basis[0]  = 0.282095f;
            basis[1]  = -0.488603f * y;
            basis[2]  = 0.488603f * z;
            basis[3]  = -0.488603f * x;
            basis[4]  = 1.092548f * x * y;
            basis[5]  = -1.092548f * y * z;
            basis[6]  = 0.315392f * (3.f * zz - 1.f);
            basis[7]  = -1.092548f * x * z;
            basis[8]  = 0.546274f * (xx - yy);
            basis[9]  = -0.590044f * y * (3.f * xx - yy);
            basis[10] = 2.890611f * x * y * z;
            basis[11] = -0.457046f * y * (5.f * zz - 1.f);
            basis[12] = 0.373176f * z * (5.f * zz - 3.f);
            basis[13] = -0.457046f * x * (5.f * zz - 1.f);
            basis[14] = 1.445306f * z * (xx - yy);
            basis[15] = -0.590044f * x * (xx - 3.f * yy);
            const float4* sh4 = (const float4*)(sh + g * 48);
            float4 S[12];
#pragma unroll
            for (int k = 0; k < 12; k++) S[k] = sh4[k];
            const float* shf = (const float*)S;
            float cr = 0.f, cg = 0.f, cb = 0.f;
#pragma unroll
            for (int k = 0; k < 16; k++) {
                cr += basis[k] * shf[3 * k + 0];
                cg += basis[k] * shf[3 * k + 1];
                cb += basis[k] * shf[3 * k + 2];
            }
            cr = fmaxf(cr + 0.5f, 0.f);
            cg = fmaxf(cg + 0.5f, 0.f);
            cb = fmaxf(cb + 0.5f, 0.f);
            float* rp = (float*)&srec[3 * s + 1];
            rp[2] = cr;
            rp[3] = cg;
            ((float*)&srec[3 * s + 2])[0] = cb;
        }
        // distributed rank: 4 threads per survivor, each scans 1/4 of the keys
        {
            int seg = tid & 3;
            for (int s = (tid >> 2); s < cnt; s += (TPB >> 2)) {
                unsigned long long ks = key64[s];
                int tA = (cnt * seg) >> 2;
                int tB = (cnt * (seg + 1)) >> 2;
                int partial = 0;
                for (int t = tA; t < tB; t++)
                    partial += (key64[t] < ks) ? 1 : 0;
                if (partial) atomicAdd(&rnk[s], partial);
            }
        }
        __syncthreads();
        // scatter: owner writes rank -> slot permutation
        if (slotA >= 0) ord[rnk[slotA]] = slotA;
        if (slotB >= 0) ord[rnk[slotB]] = slotB;
        __syncthreads();

        // ---- Phase C: composite. Wave w takes sorted ranks [w*L, (w+1)*L).
        int L = (cnt + NWAVE - 1) >> 4;
        int r0 = wave * L;
        int r1 = r0 + L; if (r1 > cnt) r1 = cnt;
        float T = 1.f, ar = 0.f, ag = 0.f, ab = 0.f;
        for (int r = r0; r < r1; r++) {
            int slot = ord[r];                   // LDS broadcast
            float4 f0 = srec[3 * slot + 0];      // u v a2 b2
            float4 f1 = srec[3 * slot + 1];      // c2 o2 r g
            float4 f2 = srec[3 * slot + 2];      // b - - -
            float ddx = px - f0.x;
            float ddy = py - f0.y;
            float tt = f0.z * ddx;
            tt = fmaf(f0.w, ddy, tt);            // a2*dx + b2*dy
            float qq = f1.x * ddy;               // c2*dy
            float pw = fmaf(tt, ddx, f1.y);      // quad + log2(op)
            pw = fmaf(qq, ddy, pw);
            float alpha = fminf(0.999f, fast_exp2(pw));
            float w = T * alpha;
            ar = fmaf(w, f1.z, ar);
            ag = fmaf(w, f1.w, ag);
            ab = fmaf(w, f2.x, ab);
            T -= w;                              // T *= (1 - alpha)
        }
        part[wave * 64 + lane] = make_float4(ar, ag, ab, T);
        __syncthreads();

        // fold the 16 depth-chunk partials in order; threads 0..63 = tile pixels
        if (tid < 64) {
            int p = (ty0 + (tid >> 3)) * WIDTH + tx0 + (tid & 7);
            float Tt = 1.f, r = 0.f, g = 0.f, b = 0.f;
#pragma unroll
            for (int cchunk = 0; cchunk < NWAVE; cchunk++) {
                float4 q4 = part[cchunk * 64 + tid];
                r = fmaf(Tt, q4.x, r);
                g = fmaf(Tt, q4.y, g);
                b = fmaf(Tt, q4.z, b);
                Tt *= q4.w;
            }
            out[3 * p + 0] = r;
            out[3 * p + 1] = g;
            out[3 * p + 2] = b;
        }
        if (ti + 1 < ntile) __syncthreads();   // srec/part reuse for 2nd tile
    }
}

extern "C" void kernel_launch(void* const* d_in, const int* in_sizes, int n_in,
                              void* d_out, int out_size, void* d_ws, size_t ws_size,
                              hipStream_t stream) {
    const float* means       = (const float*)d_in[0];
    const float* quats       = (const float*)d_in[1];
    const float* log_scales  = (const float*)d_in[2];
    const float* opac_logits = (const float*)d_in[3];
    const float* sh          = (const float*)d_in[4];
    const float* c2w         = (const float*)d_in[5];

    fused_kernel<<<RBLOCKS, TPB, SMEM_SZ, stream>>>(
        means, quats, log_scales, opac_logits, sh, c2w, (float*)d_out);
}

// Round 4
// 77.684 us; speedup vs baseline: 1.0984x; 1.0984x over previous
//
#include <hip/hip_runtime.h>
#include <math.h>

#define N_GAUSS 1536
#define WIDTH   160
#define HEIGHT  128
#define NPIX    (WIDTH * HEIGHT)   // 20480
#define FXC     146.44f
#define FYC     146.44f
#define CXC     80.0f
#define CYC     64.0f
#define EPS2D   0.3f
#define NEARP   0.01f
#define FARP    1e10f
#define L2E     1.4426950408889634f
#define LN2     0.6931471805599453f
#define CULL_E  25.0f              // cull where alpha <= 2^-25 (err <= 1536*2^-25 ~ 4.6e-5)

#define PREP_BLOCKS 384            // 4 gaussians/block, 1 wave (64 thr)/gaussian
#define PREP_TPB    256
#define SCAN_LEN4   (N_GAUSS / 64 / 4)  // 6 float4 per lane

#define NWAVE   16                 // waves per raster block = depth chunks
#define RCHUNK  (N_GAUSS / NWAVE)  // 96 gaussians per depth chunk
#define RPIX    64                 // pixels per raster block (one lane each)
#define TILE_W  8                  // 8x8 pixel tile: best shape for bbox culling
#define TILE_H  8
#define TILES_X (WIDTH / TILE_W)   // 20
#define TILES_Y (HEIGHT / TILE_H)  // 16

// fast 2^x: single v_exp_f32 on gfx950
__device__ __forceinline__ float fast_exp2(float x) {
    return __builtin_amdgcn_exp2f(x);
}

// Output layout (two arrays, both indexed by depth rank):
//   bbox[rank]    = (u, v, rx, ry)            -- cull AABB; masked => u=v=1e30, rx=ry=0
//   rec [2*rank]  = (a2, b2, c2, o2)          -- exp2-domain conic + log2(opacity)
//   rec [2*rank+1]= (r, g, b, 0)
// alpha = exp2(a2*dx^2 + b2*dx*dy + c2*dy^2 + o2)
// rx = sqrt(Qmax*a), ry = sqrt(Qmax*c) is the EXACT axis-aligned extent of the
// ellipse {quadform = Qmax} with Qmax = 2*ln2*(CULL_E + log2(op)): outside the
// bbox, alpha < 2^-CULL_E. det>0 strictly (PSD cov + EPS2D on diag), so the
// level set is always an ellipse and the bound is valid.

__global__ __launch_bounds__(PREP_TPB) void prep_sort_kernel(
    const float* __restrict__ means, const float* __restrict__ quats,
    const float* __restrict__ log_scales, const float* __restrict__ opac_logits,
    const float* __restrict__ sh, const float* __restrict__ c2w,
    float4* __restrict__ bbox, float4* __restrict__ rec)
{
    __shared__ float4 k4_lds[N_GAUSS / 4];
    float* k_lds = (float*)k4_lds;

    // camera: c2w is (3,4) row-major. R = c2w[:,:3] with columns 1,2 negated.
    float C[12];
#pragma unroll
    for (int k = 0; k < 12; k++) C[k] = c2w[k];
    float R00 =  C[0], R01 =  C[4], R02 =  C[8];
    float R10 = -C[1], R11 = -C[5], R12 = -C[9];
    float R20 = -C[2], R21 = -C[6], R22 = -C[10];
    float cpx = C[3], cpy = C[7], cpz = C[11];
    float t0 = -(R00 * cpx + R01 * cpy + R02 * cpz);
    float t1 = -(R10 * cpx + R11 * cpy + R12 * cpz);
    float t2 = -(R20 * cpx + R21 * cpy + R22 * cpz);

    // all 1536 keys (identical FP sequence in every block -> consistent ranks)
    for (int j = threadIdx.x; j < N_GAUSS; j += PREP_TPB) {
        float mx = means[3 * j], my = means[3 * j + 1], mz = means[3 * j + 2];
        float tzj = R20 * mx + R21 * my + R22 * mz + t2;
        bool m = (tzj > NEARP) && (tzj < FARP);
        k_lds[j] = m ? tzj : INFINITY;
    }
    __syncthreads();

    int i    = blockIdx.x * 4 + (threadIdx.x >> 6);   // gaussian index (one wave)
    int part = threadIdx.x & 63;                      // lane within the wave

    float mx = means[3 * i], my = means[3 * i + 1], mz = means[3 * i + 2];
    float4 qv = ((const float4*)quats)[i];
    float lsx = log_scales[3 * i + 0];
    float lsy = log_scales[3 * i + 1];
    float lsz = log_scales[3 * i + 2];
    float olog = opac_logits[i];
    const float4* sh4 = (const float4*)(sh + i * 48);
    float4 S[12];
#pragma unroll
    for (int k = 0; k < 12; k++) S[k] = sh4[k];
    const float* shf = (const float*)S;

    float tx = R00 * mx + R01 * my + R02 * mz + t0;
    float ty = R10 * mx + R11 * my + R12 * mz + t1;
    float tz = R20 * mx + R21 * my + R22 * mz + t2;
    bool mask = (tz > NEARP) && (tz < FARP);

    // view dir + SH color
    float dx = mx - cpx, dy = my - cpy, dz = mz - cpz;
    float rn = rsqrtf(dx * dx + dy * dy + dz * dz);
    float x = dx * rn, y = dy * rn, z = dz * rn;
    float xx = x * x, yy = y * y, zz = z * z;
    float basis[16];
    basis[0]  = 0.282095f;
    basis[1]  = -0.488603f * y;
    basis[2]  = 0.488603f * z;
    basis[3]  = -0.488603f * x;
    basis[4]  = 1.092548f * x * y;
    basis[5]  = -1.092548f * y * z;
    basis[6]  = 0.315392f * (3.f * zz - 1.f);
    basis[7]  = -1.092548f * x * z;
    basis[8]  = 0.546274f * (xx - yy);
    basis[9]  = -0.590044f * y * (3.f * xx - yy);
    basis[10] = 2.890611f * x * y * z;
    basis[11] = -0.457046f * y * (5.f * zz - 1.f);
    basis[12] = 0.373176f * z * (5.f * zz - 3.f);
    basis[13] = -0.457046f * x * (5.f * zz - 1.f);
    basis[14] = 1.445306f * z * (xx - yy);
    basis[15] = -0.590044f * x * (xx - 3.f * yy);
    float cr = 0.f, cg = 0.f, cb = 0.f;
#pragma unroll
    for (int k = 0; k < 16; k++) {
        cr += basis[k] * shf[3 * k + 0];
        cg += basis[k] * shf[3 * k + 1];
        cb += basis[k] * shf[3 * k + 2];
    }
    cr = fmaxf(cr + 0.5f, 0.f);
    cg = fmaxf(cg + 0.5f, 0.f);
    cb = fmaxf(cb + 0.5f, 0.f);

    // quat -> rot, scaled columns, cov3d = M M^T
    float qw = qv.x, qx = qv.y, qy = qv.z, qz = qv.w;
    float qn = rsqrtf(qw * qw + qx * qx + qy * qy + qz * qz);
    qw *= qn; qx *= qn; qy *= qn; qz *= qn;
    float sx = expf(lsx);
    float sy = expf(lsy);
    float sz = expf(lsz);
    float M00 = (1.f - 2.f * (qy * qy + qz * qz)) * sx;
    float M01 = (2.f * (qx * qy - qz * qw)) * sy;
    float M02 = (2.f * (qx * qz + qy * qw)) * sz;
    float M10 = (2.f * (qx * qy + qz * qw)) * sx;
    float M11 = (1.f - 2.f * (qx * qx + qz * qz)) * sy;
    float M12 = (2.f * (qy * qz - qx * qw)) * sz;
    float M20 = (2.f * (qx * qz - qy * qw)) * sx;
    float M21 = (2.f * (qy * qz + qx * qw)) * sy;
    float M22 = (1.f - 2.f * (qx * qx + qy * qy)) * sz;
    float V00 = M00 * M00 + M01 * M01 + M02 * M02;
    float V01 = M00 * M10 + M01 * M11 + M02 * M12;
    float V02 = M00 * M20 + M01 * M21 + M02 * M22;
    float V11 = M10 * M10 + M11 * M11 + M12 * M12;
    float V12 = M10 * M20 + M11 * M21 + M12 * M22;
    float V22 = M20 * M20 + M21 * M21 + M22 * M22;

    // cov_cam = Rw V Rw^T
    float T00 = R00 * V00 + R01 * V01 + R02 * V02;
    float T01 = R00 * V01 + R01 * V11 + R02 * V12;
    float T02 = R00 * V02 + R01 * V12 + R02 * V22;
    float T10 = R10 * V00 + R11 * V01 + R12 * V02;
    float T11 = R10 * V01 + R11 * V11 + R12 * V12;
    float T12 = R10 * V02 + R11 * V12 + R12 * V22;
    float T20 = R20 * V00 + R21 * V01 + R22 * V02;
    float T21 = R20 * V01 + R21 * V11 + R22 * V12;
    float T22 = R20 * V02 + R21 * V12 + R22 * V22;
    float cc00 = T00 * R00 + T01 * R01 + T02 * R02;
    float cc01 = T00 * R10 + T01 * R11 + T02 * R12;
    float cc02 = T00 * R20 + T01 * R21 + T02 * R22;
    float cc11 = T10 * R10 + T11 * R11 + T12 * R12;
    float cc12 = T10 * R20 + T11 * R21 + T12 * R22;
    float cc22 = T20 * R20 + T21 * R21 + T22 * R22;

    // projection Jacobian, cov2d = J cov_cam J^T
    float rz = 1.f / tz;
    float rz2 = rz * rz;
    float j00 = FXC * rz, j02 = -FXC * tx * rz2;
    float j11 = FYC * rz, j12 = -FYC * ty * rz2;
    float c2d00 = j00 * j00 * cc00 + 2.f * j00 * j02 * cc02 + j02 * j02 * cc22;
    float c2d01 = (j00 * cc01 + j02 * cc12) * j11 + (j00 * cc02 + j02 * cc22) * j12;
    float c2d11 = j11 * j11 * cc11 + 2.f * j11 * j12 * cc12 + j12 * j12 * cc22;

    float a = c2d00 + EPS2D, c = c2d11 + EPS2D, b = c2d01;
    float idet = 1.f / (a * c - b * b);
    float Ac = c * idet, Bc = -b * idet, Cc = a * idet;
    float u = FXC * tx * rz + CXC;
    float v = FYC * ty * rz + CYC;
    float op = 1.f / (1.f + expf(-olog));
    float a2 = -0.5f * L2E * Ac;
    float b2 = -L2E * Bc;
    float c2 = -0.5f * L2E * Cc;
    float o2 = log2f(op);

    // conservative cull AABB (exact ellipse extents at alpha = 2^-CULL_E)
    float Qmax = fmaxf(0.f, 2.f * LN2 * (CULL_E + o2));
    float rx = sqrtf(Qmax * a);
    float ry = sqrtf(Qmax * c);

    if (!mask) {                       // never drawn: push bbox off to infinity
        u = 1e30f; v = 1e30f; rx = 0.f; ry = 0.f;
        a2 = 0.f; b2 = 0.f; c2 = 0.f; o2 = -INFINITY;
    }

    // stable ascending partial rank over this lane's 1/64th of the keys
    float ki = k_lds[i];
    int rank = 0;
    int base4 = part * SCAN_LEN4;
#pragma unroll
    for (int jj = 0; jj < SCAN_LEN4; jj++) {
        int j4 = base4 + jj;
        float4 kk = k4_lds[j4];
        int j = 4 * j4;
        rank += (kk.x < ki) || (kk.x == ki && (j + 0) < i);
        rank += (kk.y < ki) || (kk.y == ki && (j + 1) < i);
        rank += (kk.z < ki) || (kk.z == ki && (j + 2) < i);
        rank += (kk.w < ki) || (kk.w == ki && (j + 3) < i);
    }
    rank += __shfl_xor(rank, 1);
    rank += __shfl_xor(rank, 2);
    rank += __shfl_xor(rank, 4);
    rank += __shfl_xor(rank, 8);
    rank += __shfl_xor(rank, 16);
    rank += __shfl_xor(rank, 32);

    if (part == 0) {
        bbox[rank]        = make_float4(u, v, rx, ry);
        rec[2 * rank]     = make_float4(a2, b2, c2, o2);
        rec[2 * rank + 1] = make_float4(cr, cg, cb, 0.f);
    }
}

// Fused raster + combine with tile culling: one block = one 8x8 pixel tile,
// 16 waves = 16 depth chunks of 96 gaussians. Each wave first loads the
// bboxes of its chunk VECTORIZED (lane g tests gaussian g: coalesced
// global_load_dwordx4, one latency), builds a survivor mask via __ballot
// (SGPR), then walks only the set bits (s_ff1). Survivor conic/color records
// are read via wave-uniform addresses -> SCALAR loads (R12 lesson kept:
// never per-lane loads of uniform data). Culled gaussians cost ~0 VALU and
// zero record loads; the compositing math over survivors is unchanged, so
// the result differs from dense only by alpha < 2^-25 tails (<= 4.6e-5).
// 16 KB LDS + ~1024 threads -> 2 blocks/CU co-resident; 320 blocks
// self-balance (measured best: this exact structure = 78.56 us).
__global__ __launch_bounds__(1024) void raster_kernel(
    const float4* __restrict__ bbox, const float4* __restrict__ rec,
    float* __restrict__ out)
{
    __shared__ float4 part_lds[NWAVE * RPIX];

    int wave = __builtin_amdgcn_readfirstlane(threadIdx.x >> 6);  // SGPR
    int lane = threadIdx.x & 63;

    int tile = blockIdx.x;                 // 20 x 16 tiles
    int tx0 = (tile % TILES_X) * TILE_W;
    int ty0 = (tile / TILES_X) * TILE_H;
    float px = (float)(tx0 + (lane & 7));
    float py = (float)(ty0 + (lane >> 3));
    float tcx = (float)tx0 + 3.5f;         // tile center; max pixel offset 3.5
    float tcy = (float)ty0 + 3.5f;

    int g0 = wave * RCHUNK;

    float T = 1.f, cr = 0.f, cg = 0.f, cb = 0.f;
#pragma unroll
    for (int bseg = 0; bseg < 2; bseg++) {       // 96 = 64 + 32 test batches
        int gbase = g0 + (bseg ? 64 : 0);
        int bn    = bseg ? 32 : 64;
        // vectorized bbox test: lane l tests gaussian gbase+l
        float4 bb = bbox[gbase + (lane < bn ? lane : 0)];
        bool ok = (lane < bn) &&
                  (fabsf(tcx - bb.x) <= bb.z + 3.5f) &&
                  (fabsf(tcy - bb.y) <= bb.w + 3.5f);
        unsigned long long m = __ballot(ok);     // wave-uniform survivor mask
        while (m) {
            int bl = __ffsll(m) - 1;             // SALU s_ff1
            m &= m - 1;
            float u = __shfl(bb.x, bl);          // readlane (uniform index)
            float v = __shfl(bb.y, bl);
            int g = gbase + bl;                  // uniform -> scalar loads
            float4 f1 = rec[2 * g];              // a2 b2 c2 o2
            float4 f2 = rec[2 * g + 1];          // r g b -
            float dx = px - u;
            float dy = py - v;
            float t  = f1.x * dx;
            t = fmaf(f1.y, dy, t);               // a2*dx + b2*dy
            float q  = f1.z * dy;                // c2*dy
            float pw = fmaf(t, dx, f1.w);        // quad + log2(op)
            pw = fmaf(q, dy, pw);
            float alpha = fminf(0.999f, fast_exp2(pw));
            float w = T * alpha;
            cr = fmaf(w, f2.x, cr);
            cg = fmaf(w, f2.y, cg);
            cb = fmaf(w, f2.z, cb);
            T -= w;                              // T *= (1 - alpha)
        }
    }
    part_lds[wave * RPIX + lane] = make_float4(cr, cg, cb, T);
    __syncthreads();

    // fold the 16 depth-chunk partials in order; threads 0..63 = tile pixels
    if (threadIdx.x < RPIX) {
        int l = threadIdx.x;
        int p = (ty0 + (l >> 3)) * WIDTH + tx0 + (l & 7);
        float Tt = 1.f, r = 0.f, g = 0.f, b = 0.f;
#pragma unroll
        for (int c = 0; c < NWAVE; c++) {
            float4 q = part_lds[c * RPIX + l];
            r = fmaf(Tt, q.x, r);
            g = fmaf(Tt, q.y, g);
            b = fmaf(Tt, q.z, b);
            Tt *= q.w;
        }
        out[3 * p + 0] = r;
        out[3 * p + 1] = g;
        out[3 * p + 2] = b;
    }
}

extern "C" void kernel_launch(void* const* d_in, const int* in_sizes, int n_in,
                              void* d_out, int out_size, void* d_ws, size_t ws_size,
                              hipStream_t stream) {
    const float* means       = (const float*)d_in[0];
    const float* quats       = (const float*)d_in[1];
    const float* log_scales  = (const float*)d_in[2];
    const float* opac_logits = (const float*)d_in[3];
    const float* sh          = (const float*)d_in[4];
    const float* c2w         = (const float*)d_in[5];

    float* ws = (float*)d_ws;
    float4* bbox = (float4*)ws;                       // 1536 * 16 B
    float4* rec  = (float4*)(ws + N_GAUSS * 4);       // 1536 * 32 B

    prep_sort_kernel<<<PREP_BLOCKS, PREP_TPB, 0, stream>>>(
        means, quats, log_scales, opac_logits, sh, c2w, bbox, rec);
    raster_kernel<<<TILES_X * TILES_Y, NWAVE * 64, 0, stream>>>(
        bbox, rec, (float*)d_out);
}